// Round 7
// baseline (137.261 us; speedup 1.0000x reference)
//
#include <hip/hip_runtime.h>

// positions [N,3] f32, node_feat [N,1] f32, w0 [1] f32, w1 [3] f32,
// edge_src [E] i32, edge_dst [E] i32  ->  out [N,4] f32
//
// R7 structure (measured rationale):
//  - global atomics: hard cap ~22 G ops/s (32 B EA transaction each,
//    scope-insensitive, R1-R4) -> avoided entirely.
//  - R6 phaseA was gather-transaction-bound: 6 divergent scalar pos loads
//    per edge. Fix: repack pos into float4[N] once, gather 2 dwordx4/edge.
//  - R6 phaseB wasted ~half its ops on 64 KB tile init/flush (507 tiles,
//    2 blk/CU). Fix: CHUNK 4096 (32 KB LDS, 4 blk/CU), SUBS=12 -> 300
//    tiles, accR 33->9.8 MB.
//
// Pipeline: repack -> phaseA (bin edges into per-chunk packed records,
// LDS histogram + ~40k returning global atomics total) -> phaseB (LDS u64
// accumulate per chunk-replica, plain-store flush) -> finalize (merge 12
// replicas, decode fixed-point, weight).
//
// Record (u64): local(12b)<<27 | fx(9b)<<18 | fy(9b)<<9 | fz(9b),
//   f? = 128 + round(sh_?*128) in [0,256].
// Accum cell (u64): fx<<48 | fy<<32 | fz<<16 | count. Per-(node,sub)
//   field sums <= 256*deg_max(~70) << 65536 -> no carry.
// Decode: sum_sh = F/128 - count.  (absmax 7.8e-3, stable R3-R6)

#define EPS 1e-12f
#define FSCALE 128.0f
#define FBIAS 128
#define CHUNK_SHIFT 12
#define CHUNK 4096
#define NCHUNK_MAX 32
#define BLKA 512
#define TPA 4
#define BLKB 512
#define SUBS 12

// ---------------- repack: pos [N,3] -> pos4 [N] (aligned 16B) ------------
__global__ void repack_pos(const float* __restrict__ pos,
                           float4* __restrict__ pos4, int n_nodes) {
    int n = blockIdx.x * blockDim.x + threadIdx.x;
    if (n >= n_nodes) return;
    float4 p;
    p.x = pos[3 * n + 0];
    p.y = pos[3 * n + 1];
    p.z = pos[3 * n + 2];
    p.w = 0.f;
    pos4[n] = p;
}

__device__ __forceinline__ unsigned long long make_rec(const float4* __restrict__ pos4,
                                                       int s, int d) {
    float4 pd = pos4[d];
    float4 ps = pos4[s];
    float rx = pd.x - ps.x;
    float ry = pd.y - ps.y;
    float rz = pd.z - ps.z;
    float nrm = sqrtf(rx * rx + ry * ry + rz * rz);
    float inv = 1.0f / fmaxf(nrm, EPS);
    unsigned fx = (unsigned)(FBIAS + (int)rintf(rx * inv * FSCALE));
    unsigned fy = (unsigned)(FBIAS + (int)rintf(ry * inv * FSCALE));
    unsigned fz = (unsigned)(FBIAS + (int)rintf(rz * inv * FSCALE));
    unsigned local = (unsigned)d & (CHUNK - 1);
    return ((unsigned long long)local << 27)
         | ((unsigned long long)fx << 18)
         | ((unsigned long long)fy << 9)
         | (unsigned long long)fz;
}

// ---------------- Phase A: bin edges into per-chunk record buckets --------
__global__ __launch_bounds__(BLKA) void phaseA(
        const float4* __restrict__ pos4,
        const int* __restrict__ dst,
        const int* __restrict__ src,
        unsigned* __restrict__ gcnt,                 // [n_chunk]
        unsigned long long* __restrict__ recs,       // [n_chunk][cap]
        int n_edges, int cap, int n_chunk) {
    __shared__ unsigned h[NCHUNK_MAX];
    __shared__ unsigned base[NCHUNK_MAX];
    int tid = threadIdx.x;
    if (tid < n_chunk) h[tid] = 0;
    __syncthreads();

    long e0 = (long)blockIdx.x * (BLKA * TPA);
    unsigned long long rec[TPA];
    int ch[TPA];
    unsigned rank[TPA];
    bool val[TPA];
#pragma unroll
    for (int t = 0; t < TPA; ++t) {
        long j = e0 + (long)t * BLKA + tid;
        val[t] = (j < n_edges);
        if (val[t]) {
            int d = dst[j];
            int s = src[j];
            ch[t] = d >> CHUNK_SHIFT;
            rec[t] = make_rec(pos4, s, d);
            rank[t] = atomicAdd(&h[ch[t]], 1u);
        }
    }
    __syncthreads();
    if (tid < n_chunk) base[tid] = h[tid] ? atomicAdd(&gcnt[tid], h[tid]) : 0u;
    __syncthreads();
#pragma unroll
    for (int t = 0; t < TPA; ++t) {
        if (val[t]) {
            unsigned idx = base[ch[t]] + rank[t];
            if (idx < (unsigned)cap)
                recs[(size_t)ch[t] * (unsigned)cap + idx] = rec[t];
        }
    }
}

// ---------------- Phase B: accumulate one bucket slice into LDS ----------
__global__ __launch_bounds__(BLKB) void phaseB(
        const unsigned* __restrict__ gcnt,
        const unsigned long long* __restrict__ recs,
        unsigned long long* __restrict__ accR,       // [SUBS][n_chunk*CHUNK]
        int cap, int n_chunk, int padded) {
    __shared__ unsigned long long lds[CHUNK];
    int c   = (int)blockIdx.x % n_chunk;
    int sub = (int)blockIdx.x / n_chunk;
    unsigned cnt = gcnt[c];
    if (cnt > (unsigned)cap) cnt = (unsigned)cap;

    for (int i = threadIdx.x; i < CHUNK; i += BLKB) lds[i] = 0ull;
    __syncthreads();

    const unsigned long long* bucket = recs + (size_t)c * (unsigned)cap;
    for (unsigned j = sub * BLKB + threadIdx.x; j < cnt; j += SUBS * BLKB) {
        unsigned long long r = bucket[j];
        unsigned local = (unsigned)(r >> 27);
        unsigned long long p = (((r >> 18) & 511ull) << 48)
                             | (((r >>  9) & 511ull) << 32)
                             | (((r      ) & 511ull) << 16)
                             | 1ull;
        atomicAdd(&lds[local], p);
    }
    __syncthreads();

    unsigned long long* row = accR + (size_t)sub * (unsigned)padded
                                   + (size_t)c * CHUNK;
    for (int i = threadIdx.x; i < CHUNK; i += BLKB) row[i] = lds[i];
}

// ---------------- Finalize: merge replicas, decode, weight ---------------
__global__ void finalize_binned(const unsigned long long* __restrict__ accR,
                                const float* __restrict__ feat,
                                const float* __restrict__ w0,
                                const float* __restrict__ w1,
                                float* __restrict__ out,
                                int n_nodes, int padded) {
    int n = blockIdx.x * blockDim.x + threadIdx.x;
    if (n >= n_nodes) return;
    int Fx = 0, Fy = 0, Fz = 0, C = 0;
    for (int s = 0; s < SUBS; ++s) {
        unsigned long long v = accR[(size_t)s * (unsigned)padded + (unsigned)n];
        Fx += (int)(v >> 48);
        Fy += (int)((v >> 32) & 0xffffull);
        Fz += (int)((v >> 16) & 0xffffull);
        C  += (int)(v & 0xffffull);
    }
    float c = (float)C;
    float rd = 1.0f / fmaxf(c, 1.0f);
    float sx = (float)Fx * (1.0f / FSCALE) - c;
    float sy = (float)Fy * (1.0f / FSCALE) - c;
    float sz = (float)Fz * (1.0f / FSCALE) - c;
    float f = feat[n];
    float4 o;
    o.x = w0[0] * f * c * rd;
    o.y = w1[0] * f * sx * rd;
    o.z = w1[1] * f * sy * rd;
    o.w = w1[2] * f * sz * rd;
    ((float4*)out)[n] = o;
}

// ---------------- Fallback (R3, known-good 224 us) -----------------------
__global__ void edge_kernel_agent(const float* __restrict__ pos,
                                  const int* __restrict__ dst,
                                  const int* __restrict__ src,
                                  unsigned long long* __restrict__ acc,
                                  int n_edges, int n_nodes, int rmask) {
    int i = blockIdx.x * blockDim.x + threadIdx.x;
    if (i >= n_edges) return;
    int s = src[i];
    int d = dst[i];
    float rx = pos[3 * d + 0] - pos[3 * s + 0];
    float ry = pos[3 * d + 1] - pos[3 * s + 1];
    float rz = pos[3 * d + 2] - pos[3 * s + 2];
    float nrm = sqrtf(rx * rx + ry * ry + rz * rz);
    float inv = 1.0f / fmaxf(nrm, EPS);
    unsigned fx = (unsigned)(FBIAS + (int)rintf(rx * inv * FSCALE));
    unsigned fy = (unsigned)(FBIAS + (int)rintf(ry * inv * FSCALE));
    unsigned fz = (unsigned)(FBIAS + (int)rintf(rz * inv * FSCALE));
    unsigned long long p = ((unsigned long long)fx << 48)
                         | ((unsigned long long)fy << 32)
                         | ((unsigned long long)fz << 16) | 1ull;
    unsigned r = (unsigned)blockIdx.x & (unsigned)rmask;
    atomicAdd(acc + (size_t)r * (unsigned)n_nodes + (unsigned)d, p);
}

__global__ void finalize_flat(const unsigned long long* __restrict__ acc,
                              const float* __restrict__ feat,
                              const float* __restrict__ w0,
                              const float* __restrict__ w1,
                              float* __restrict__ out,
                              int n_nodes, int R) {
    int n = blockIdx.x * blockDim.x + threadIdx.x;
    if (n >= n_nodes) return;
    int Fx = 0, Fy = 0, Fz = 0, C = 0;
    for (int r = 0; r < R; ++r) {
        unsigned long long v = acc[(size_t)r * n_nodes + n];
        Fx += (int)(v >> 48);
        Fy += (int)((v >> 32) & 0xffffull);
        Fz += (int)((v >> 16) & 0xffffull);
        C  += (int)(v & 0xffffull);
    }
    float c = (float)C;
    float rd = 1.0f / fmaxf(c, 1.0f);
    float sx = (float)Fx * (1.0f / FSCALE) - c;
    float sy = (float)Fy * (1.0f / FSCALE) - c;
    float sz = (float)Fz * (1.0f / FSCALE) - c;
    float f = feat[n];
    float4 o;
    o.x = w0[0] * f * c * rd;
    o.y = w1[0] * f * sx * rd;
    o.z = w1[1] * f * sy * rd;
    o.w = w1[2] * f * sz * rd;
    ((float4*)out)[n] = o;
}

extern "C" void kernel_launch(void* const* d_in, const int* in_sizes, int n_in,
                              void* d_out, int out_size, void* d_ws, size_t ws_size,
                              hipStream_t stream) {
    const float* pos  = (const float*)d_in[0];
    const float* feat = (const float*)d_in[1];
    const float* w0   = (const float*)d_in[2];
    const float* w1   = (const float*)d_in[3];
    const int* esrc   = (const int*)d_in[4];
    const int* edst   = (const int*)d_in[5];
    int n_nodes = in_sizes[0] / 3;
    int n_edges = in_sizes[4];

    int n_chunk = (n_nodes + CHUNK - 1) >> CHUNK_SHIFT;      // 25 for 100k
    int padded  = n_chunk * CHUNK;
    int cap = (int)((long)n_edges * CHUNK / n_nodes + 8192);

    size_t off_pos4 = 0;
    size_t pos4_bytes = (size_t)padded * sizeof(float4);
    size_t off_gcnt = (pos4_bytes + 255) & ~(size_t)255;
    size_t off_recs = off_gcnt + 256;
    size_t recs_bytes = (size_t)n_chunk * (unsigned)cap * sizeof(unsigned long long);
    size_t off_accR = off_recs + ((recs_bytes + 255) & ~(size_t)255);
    size_t accR_bytes = (size_t)SUBS * (unsigned)padded * sizeof(unsigned long long);
    size_t need = off_accR + accR_bytes;

    int nb = 256;
    int ng = (n_nodes + nb - 1) / nb;

    if (n_chunk <= NCHUNK_MAX && ws_size >= need) {
        float4* pos4 = (float4*)((char*)d_ws + off_pos4);
        unsigned* gcnt = (unsigned*)((char*)d_ws + off_gcnt);
        unsigned long long* recs = (unsigned long long*)((char*)d_ws + off_recs);
        unsigned long long* accR = (unsigned long long*)((char*)d_ws + off_accR);

        hipMemsetAsync(gcnt, 0, (size_t)n_chunk * sizeof(unsigned), stream);
        repack_pos<<<ng, nb, 0, stream>>>(pos, pos4, n_nodes);

        int ga = (int)((n_edges + (long)BLKA * TPA - 1) / ((long)BLKA * TPA));
        phaseA<<<ga, BLKA, 0, stream>>>(pos4, edst, esrc, gcnt, recs,
                                        n_edges, cap, n_chunk);
        phaseB<<<n_chunk * SUBS, BLKB, 0, stream>>>(gcnt, recs, accR,
                                                    cap, n_chunk, padded);
        finalize_binned<<<ng, nb, 0, stream>>>(accR, feat, w0, w1,
                                               (float*)d_out, n_nodes, padded);
    } else {
        // fallback: R3 known-good agent-atomic path
        int R = 4;
        while (R > 1 && (size_t)R * n_nodes * sizeof(unsigned long long) > ws_size) R >>= 1;
        unsigned long long* acc = (unsigned long long*)d_ws;
        hipMemsetAsync(acc, 0, (size_t)R * n_nodes * sizeof(unsigned long long), stream);
        int eb = 256;
        int eg = (n_edges + eb - 1) / eb;
        edge_kernel_agent<<<eg, eb, 0, stream>>>(pos, edst, esrc, acc,
                                                 n_edges, n_nodes, R - 1);
        finalize_flat<<<ng, nb, 0, stream>>>(acc, feat, w0, w1,
                                             (float*)d_out, n_nodes, R);
    }
}